// Round 5
// baseline (55.997 us; speedup 1.0000x reference)
//
#include <hip/hip_runtime.h>

#define B_DIM 8
#define N_DIM 512
#define NPAIR (B_DIM * N_DIM * N_DIM)   // 2,097,152

#define C0     0.28209479177387814f   // sqrt(1/(4pi))
#define C1     0.4886025119029199f    // sqrt(3/(4pi))
#define KXY    0.34549414947133544f   // C1 / sqrt(2)
#define SCALE2 3.2360432f             // sqrt(10pi/3)
#define SCALE3 3.1263148f             // sqrt(28pi/9)

// LDS image of one block's contiguous output regions (floats):
// [0,1536)     psi1  : pair-major, 6 f/pair * 256
// [1536,4096)  psi2  : 10 f/pair * 256
// [4096,7680)  psi3  : 14 f/pair * 256
// [7680,7936)  norms : 1 f/pair * 256
#define L1_OFF 0
#define L2_OFF 1536
#define L3_OFF 4096
#define LN_OFF 7680
#define LDS_FLOATS 7936   // 31744 B -> 5 blocks/CU (158.7 of 160 KiB)

typedef float fx4 __attribute__((ext_vector_type(4)));   // native vector: legal for nontemporal builtins

__device__ __forceinline__ void cmul(float ar, float ai, float br, float bi,
                                     float& cr, float& ci) {
    cr = ar * br - ai * bi;
    ci = ar * bi + ai * br;
}

__device__ __forceinline__ void nt_store4(fx4* dst, fx4 v) {
    __builtin_nontemporal_store(v, dst);
}

__global__ __launch_bounds__(256) void sph_lds_nt_kernel(
    const float* __restrict__ pos1,
    const float* __restrict__ pos2,
    float* __restrict__ out)
{
    __shared__ float st[LDS_FLOATS];

    const int t  = threadIdx.x;
    const int p0 = blockIdx.x << 8;          // first pair of this block
    const int p  = p0 + t;
    const int row = p0 >> 9;                 // uniform: b*512 + i
    const int b   = p0 >> 18;                // uniform
    const int j   = p & (N_DIM - 1);

    const float* a1 = pos1 + (size_t)row * 3;               // uniform
    const float* a2 = pos2 + ((size_t)(b << 9) + j) * 3;    // per-lane

    float* o0 = out;                       // psi0:  2 f/pair (constant)
    float* o1 = out + (size_t)2  * NPAIR;  // psi1:  6 f/pair
    float* o2 = out + (size_t)8  * NPAIR;  // psi2: 10 f/pair
    float* o3 = out + (size_t)18 * NPAIR;  // psi3: 14 f/pair
    float* o4 = out + (size_t)32 * NPAIR;  // norms: 1 f/pair

    // psi0 early: independent of LDS, drains during the barrier wait.
    if (t < 128) {
        fx4* g0 = (fx4*)(o0 + (size_t)p0 * 2);
        nt_store4(g0 + t, (fx4){C0, 0.0f, C0, 0.0f});
    }

    const float rx = a1[0] - a2[0];
    const float ry = a1[1] - a2[1];
    const float rz = a1[2] - a2[2];
    const float r2 = rx * rx + ry * ry + rz * rz;
    const float norm = sqrtf(r2);
    const float rn = (r2 > 0.0f) ? rsqrtf(r2) : 0.0f;

    const float x = rx * rn;
    const float y = ry * rn;
    const float z = rz * rn;

    // l=1
    float br_[3], bi_[3];
    br_[0] =  KXY * x;  bi_[0] = -KXY * y;
    br_[1] =  C1  * z;  bi_[1] = 0.0f;
    br_[2] = -KXY * x;  bi_[2] = -KXY * y;

    float2* s1 = (float2*)(st + L1_OFF + t * 6);
    s1[0] = make_float2(br_[0], bi_[0]);
    s1[1] = make_float2(br_[1], bi_[1]);
    s1[2] = make_float2(br_[2], bi_[2]);

    // l=2
    const float W2[3][5] = {
        {1.0f,        0.70710678f, 0.40824829f, 0.0f,        0.0f},
        {0.0f,        0.70710678f, 0.81649658f, 0.70710678f, 0.0f},
        {0.0f,        0.0f,        0.40824829f, 0.70710678f, 1.0f}};
    float q2r[5], q2i[5];
    float2* s2 = (float2*)(st + L2_OFF + t * 10);
#pragma unroll
    for (int mi = 0; mi < 5; ++mi) {
        float sr = 0.0f, si = 0.0f;
#pragma unroll
        for (int m1i = 0; m1i < 3; ++m1i) {
            const int pidx = mi - m1i;
            if (pidx < 0 || pidx > 2) continue;
            const float w = W2[m1i][mi];
            if (w == 0.0f) continue;
            float cr, ci;
            cmul(br_[m1i], bi_[m1i], br_[pidx], bi_[pidx], cr, ci);
            sr += w * cr; si += w * ci;
        }
        q2r[mi] = sr * SCALE2;
        q2i[mi] = si * SCALE2;
        s2[mi] = make_float2(q2r[mi], q2i[mi]);
    }

    // l=3
    const float W3[3][7] = {
        {1.0f,        0.81649658f, 0.63245553f, 0.44721360f, 0.25819889f, 0.0f,        0.0f},
        {0.0f,        0.57735027f, 0.73029674f, 0.77459667f, 0.73029674f, 0.57735027f, 0.0f},
        {0.0f,        0.0f,        0.25819889f, 0.44721360f, 0.63245553f, 0.81649658f, 1.0f}};
    float2* s3 = (float2*)(st + L3_OFF + t * 14);
#pragma unroll
    for (int mi = 0; mi < 7; ++mi) {
        float sr = 0.0f, si = 0.0f;
#pragma unroll
        for (int m1i = 0; m1i < 3; ++m1i) {
            const int pidx = mi - m1i;
            if (pidx < 0 || pidx > 4) continue;
            const float w = W3[m1i][mi];
            if (w == 0.0f) continue;
            float cr, ci;
            cmul(br_[m1i], bi_[m1i], q2r[pidx], q2i[pidx], cr, ci);
            sr += w * cr; si += w * ci;
        }
        s3[mi] = make_float2(sr * SCALE3, si * SCALE3);
    }

    st[LN_OFF + t] = norm;

    __syncthreads();

    // ---- cooperative copy-out: lane-contiguous nontemporal float4 stores ----
    const fx4* l4;
    fx4* g4;

    // psi1: 1536 floats = 384 fx4
    l4 = (const fx4*)(st + L1_OFF);
    g4 = (fx4*)(o1 + (size_t)p0 * 6);
    { int idx = t;            nt_store4(g4 + idx, l4[idx]);
      if ((idx += 256) < 384) nt_store4(g4 + idx, l4[idx]); }

    // psi2: 2560 floats = 640 fx4
    l4 = (const fx4*)(st + L2_OFF);
    g4 = (fx4*)(o2 + (size_t)p0 * 10);
    { int idx = t;            nt_store4(g4 + idx, l4[idx]);
      idx += 256;             nt_store4(g4 + idx, l4[idx]);
      if ((idx += 256) < 640) nt_store4(g4 + idx, l4[idx]); }

    // psi3: 3584 floats = 896 fx4
    l4 = (const fx4*)(st + L3_OFF);
    g4 = (fx4*)(o3 + (size_t)p0 * 14);
    { int idx = t;            nt_store4(g4 + idx, l4[idx]);
      idx += 256;             nt_store4(g4 + idx, l4[idx]);
      idx += 256;             nt_store4(g4 + idx, l4[idx]);
      if ((idx += 256) < 896) nt_store4(g4 + idx, l4[idx]); }

    // norms: 256 floats = 64 fx4
    if (t < 64) {
        l4 = (const fx4*)(st + LN_OFF);
        g4 = (fx4*)(o4 + (size_t)p0);
        nt_store4(g4 + t, l4[t]);
    }
}

extern "C" void kernel_launch(void* const* d_in, const int* in_sizes, int n_in,
                              void* d_out, int out_size, void* d_ws, size_t ws_size,
                              hipStream_t stream) {
    (void)in_sizes; (void)n_in; (void)d_ws; (void)ws_size; (void)out_size;
    const float* pos1 = (const float*)d_in[0];
    const float* pos2 = (const float*)d_in[1];
    float* out = (float*)d_out;

    const int threads = 256;
    const int blocks = NPAIR / threads;   // 8192 blocks
    sph_lds_nt_kernel<<<blocks, threads, 0, stream>>>(pos1, pos2, out);
}

// Round 6
// 45.928 us; speedup vs baseline: 1.2192x; 1.2192x over previous
//
#include <hip/hip_runtime.h>

#define B_DIM 8
#define N_DIM 512
#define NPAIR (B_DIM * N_DIM * N_DIM)   // 2,097,152

#define C0     0.28209479177387814f   // sqrt(1/(4pi))
#define C1     0.4886025119029199f    // sqrt(3/(4pi))
#define KXY    0.34549414947133544f   // C1 / sqrt(2)
#define SCALE2 3.2360432f             // sqrt(10pi/3)
#define SCALE3 3.1263148f             // sqrt(28pi/9)

// LDS image of one block's contiguous output regions (floats):
// [0,1536)     psi1  : pair-major, 6 f/pair * 256
// [1536,4096)  psi2  : 10 f/pair * 256
// [4096,7680)  psi3  : 14 f/pair * 256
// [7680,7936)  norms : 1 f/pair * 256
#define L1_OFF 0
#define L2_OFF 1536
#define L3_OFF 4096
#define LN_OFF 7680
#define LDS_FLOATS 7936   // 31744 B -> 5 blocks/CU (158.7 of 160 KiB)

__device__ __forceinline__ void cmul(float ar, float ai, float br, float bi,
                                     float& cr, float& ci) {
    cr = ar * br - ai * bi;
    ci = ar * bi + ai * br;
}

__global__ __launch_bounds__(256) void sph_lds_kernel(
    const float* __restrict__ pos1,
    const float* __restrict__ pos2,
    float* __restrict__ out)
{
    __shared__ float st[LDS_FLOATS];

    const int t  = threadIdx.x;
    const int p0 = blockIdx.x << 8;          // first pair of this block
    const int p  = p0 + t;
    const int row = p0 >> 9;                 // uniform: b*512 + i
    const int b   = p0 >> 18;                // uniform
    const int j   = p & (N_DIM - 1);

    const float* a1 = pos1 + (size_t)row * 3;               // uniform
    const float* a2 = pos2 + ((size_t)(b << 9) + j) * 3;    // per-lane

    float* o0 = out;                       // psi0:  2 f/pair (constant)
    float* o1 = out + (size_t)2  * NPAIR;  // psi1:  6 f/pair
    float* o2 = out + (size_t)8  * NPAIR;  // psi2: 10 f/pair
    float* o3 = out + (size_t)18 * NPAIR;  // psi3: 14 f/pair
    float* o4 = out + (size_t)32 * NPAIR;  // norms: 1 f/pair

    // psi0 early: independent of LDS; drains during the barrier wait.
    if (t < 128) {
        float4* g0 = (float4*)(o0 + (size_t)p0 * 2);
        g0[t] = make_float4(C0, 0.0f, C0, 0.0f);
    }

    const float rx = a1[0] - a2[0];
    const float ry = a1[1] - a2[1];
    const float rz = a1[2] - a2[2];
    const float r2 = rx * rx + ry * ry + rz * rz;
    const float norm = sqrtf(r2);
    const float rn = (r2 > 0.0f) ? rsqrtf(r2) : 0.0f;

    const float x = rx * rn;
    const float y = ry * rn;
    const float z = rz * rn;

    // l=1
    float br_[3], bi_[3];
    br_[0] =  KXY * x;  bi_[0] = -KXY * y;
    br_[1] =  C1  * z;  bi_[1] = 0.0f;
    br_[2] = -KXY * x;  bi_[2] = -KXY * y;

    float2* s1 = (float2*)(st + L1_OFF + t * 6);
    s1[0] = make_float2(br_[0], bi_[0]);
    s1[1] = make_float2(br_[1], bi_[1]);
    s1[2] = make_float2(br_[2], bi_[2]);

    // l=2
    const float W2[3][5] = {
        {1.0f,        0.70710678f, 0.40824829f, 0.0f,        0.0f},
        {0.0f,        0.70710678f, 0.81649658f, 0.70710678f, 0.0f},
        {0.0f,        0.0f,        0.40824829f, 0.70710678f, 1.0f}};
    float q2r[5], q2i[5];
    float2* s2 = (float2*)(st + L2_OFF + t * 10);
#pragma unroll
    for (int mi = 0; mi < 5; ++mi) {
        float sr = 0.0f, si = 0.0f;
#pragma unroll
        for (int m1i = 0; m1i < 3; ++m1i) {
            const int pidx = mi - m1i;
            if (pidx < 0 || pidx > 2) continue;
            const float w = W2[m1i][mi];
            if (w == 0.0f) continue;
            float cr, ci;
            cmul(br_[m1i], bi_[m1i], br_[pidx], bi_[pidx], cr, ci);
            sr += w * cr; si += w * ci;
        }
        q2r[mi] = sr * SCALE2;
        q2i[mi] = si * SCALE2;
        s2[mi] = make_float2(q2r[mi], q2i[mi]);
    }

    // l=3
    const float W3[3][7] = {
        {1.0f,        0.81649658f, 0.63245553f, 0.44721360f, 0.25819889f, 0.0f,        0.0f},
        {0.0f,        0.57735027f, 0.73029674f, 0.77459667f, 0.73029674f, 0.57735027f, 0.0f},
        {0.0f,        0.0f,        0.25819889f, 0.44721360f, 0.63245553f, 0.81649658f, 1.0f}};
    float2* s3 = (float2*)(st + L3_OFF + t * 14);
#pragma unroll
    for (int mi = 0; mi < 7; ++mi) {
        float sr = 0.0f, si = 0.0f;
#pragma unroll
        for (int m1i = 0; m1i < 3; ++m1i) {
            const int pidx = mi - m1i;
            if (pidx < 0 || pidx > 4) continue;
            const float w = W3[m1i][mi];
            if (w == 0.0f) continue;
            float cr, ci;
            cmul(br_[m1i], bi_[m1i], q2r[pidx], q2i[pidx], cr, ci);
            sr += w * cr; si += w * ci;
        }
        s3[mi] = make_float2(sr * SCALE3, si * SCALE3);
    }

    st[LN_OFF + t] = norm;

    __syncthreads();

    // ---- cooperative copy-out: fully lane-contiguous float4 stores ----
    const float4* l4;
    float4* g4;

    // psi1: 1536 floats = 384 float4
    l4 = (const float4*)(st + L1_OFF);
    g4 = (float4*)(o1 + (size_t)p0 * 6);
    for (int idx = t; idx < 384; idx += 256) g4[idx] = l4[idx];

    // psi2: 2560 floats = 640 float4
    l4 = (const float4*)(st + L2_OFF);
    g4 = (float4*)(o2 + (size_t)p0 * 10);
    for (int idx = t; idx < 640; idx += 256) g4[idx] = l4[idx];

    // psi3: 3584 floats = 896 float4
    l4 = (const float4*)(st + L3_OFF);
    g4 = (float4*)(o3 + (size_t)p0 * 14);
    for (int idx = t; idx < 896; idx += 256) g4[idx] = l4[idx];

    // norms: 256 floats = 64 float4
    if (t < 64) {
        l4 = (const float4*)(st + LN_OFF);
        g4 = (float4*)(o4 + (size_t)p0);
        g4[t] = l4[t];
    }
}

extern "C" void kernel_launch(void* const* d_in, const int* in_sizes, int n_in,
                              void* d_out, int out_size, void* d_ws, size_t ws_size,
                              hipStream_t stream) {
    (void)in_sizes; (void)n_in; (void)d_ws; (void)ws_size; (void)out_size;
    const float* pos1 = (const float*)d_in[0];
    const float* pos2 = (const float*)d_in[1];
    float* out = (float*)d_out;

    const int threads = 256;
    const int blocks = NPAIR / threads;   // 8192 blocks
    sph_lds_kernel<<<blocks, threads, 0, stream>>>(pos1, pos2, out);
}